// Round 12
// baseline (148.484 us; speedup 1.0000x reference)
//
#include <hip/hip_runtime.h>
#include <math.h>

#define NP 4
#define NN 8192
#define NM 8192

// ws layout (float units):
//   AKV: neg-cad-t f16 k-vectors, 2 x half8/point (k0..7, k8..15) -> 262144
//   BKV: cam f16 k-vectors, 2 x half8/point                      -> 262144
//   HA:  0.5|cad_t|^2 f32 per point                              -> 32768
//   HB:  0.5|cam|^2 f32 per point                                -> 32768
//   PARTA: per-(by)-slice row-min partials, 16 x 32768           -> 524288
//   PARTB: per-(bx)-slice col-min partials, 32 x 32768           -> 1048576
#define AKV_OFF 0
#define BKV_OFF 262144
#define HA_OFF  524288
#define HB_OFF  557056
#define PARTA_OFF 589824
#define PARTB_OFF 1114112
// total ws use: 2162688 floats = 8.65 MB

typedef _Float16 half8 __attribute__((ext_vector_type(8)));
typedef float float4v __attribute__((ext_vector_type(4)));

__device__ inline void split16(float v, _Float16& h, _Float16& l) {
    h = (_Float16)v;
    l = (_Float16)(v - (float)h);
}

__device__ inline void make_transform(const float* __restrict__ quat,
                                      const float* __restrict__ tra,
                                      int p, float T[12]) {
    float q0 = quat[p * 4 + 0], q1 = quat[p * 4 + 1];
    float q2 = quat[p * 4 + 2], q3 = quat[p * 4 + 3];
    float inv = 1.0f / sqrtf(q0 * q0 + q1 * q1 + q2 * q2 + q3 * q3);
    float a = q0 * inv, b = q1 * inv, c = q2 * inv, d = q3 * inv;
    T[0] = 1.0f - 2.0f * c * c - 2.0f * d * d;
    T[1] = 2.0f * b * c - 2.0f * a * d;
    T[2] = 2.0f * a * c + 2.0f * b * d;
    T[3] = tra[p * 3 + 0];
    T[4] = 2.0f * b * c + 2.0f * a * d;
    T[5] = 1.0f - 2.0f * b * b - 2.0f * d * d;
    T[6] = 2.0f * c * d - 2.0f * a * b;
    T[7] = tra[p * 3 + 1];
    T[8] = 2.0f * b * d - 2.0f * a * c;
    T[9] = 2.0f * a * b + 2.0f * c * d;
    T[10] = 1.0f - 2.0f * b * b - 2.0f * c * c;
    T[11] = tra[p * 3 + 2];
}

// 256 blocks x 256 threads over 65536 points.
// cad (idx<32768): transform, NEGATE, f16 hi/lo split, A-layout k-vec:
//   k0..8 = [nh0 nh1 nh2 nl0 nl1 nl2 nh0 nh1 nh2], rest 0.
// cam: B-layout k-vec: k0..8 = [h0 h1 h2 h0 h1 h2 l0 l1 l2].
// Sum_k A_k*B_k = -(h.h + l.h + h.l) = -S, |err| ~ |l|^2 ~ 1e-7.
// (Layouts verified on HW: R10/R11 passed with absmax 0.0.)
__global__ __launch_bounds__(256) void prep_kernel(
    const float* __restrict__ cam, const float* __restrict__ cad,
    const float* __restrict__ quat, const float* __restrict__ tra,
    float* __restrict__ ws, float* __restrict__ out) {
    int idx = blockIdx.x * 256 + threadIdx.x;  // [0, 65536)

    if (idx < NP * NM) {
        int p = idx >> 13;
        float T[12];
        make_transform(quat, tra, p, T);
        float x = cad[idx * 3 + 0];
        float y = cad[idx * 3 + 1];
        float z = cad[idx * 3 + 2];
        float vx = fmaf(T[0], x, fmaf(T[1], y, fmaf(T[2], z, T[3])));
        float vy = fmaf(T[4], x, fmaf(T[5], y, fmaf(T[6], z, T[7])));
        float vz = fmaf(T[8], x, fmaf(T[9], y, fmaf(T[10], z, T[11])));
        ws[HA_OFF + idx] = 0.5f * (vx * vx + vy * vy + vz * vz);
        _Float16 hx, lx, hy, ly, hz, lz;
        split16(-vx, hx, lx);
        split16(-vy, hy, ly);
        split16(-vz, hz, lz);
        half8 k0 = {hx, hy, hz, lx, ly, lz, hx, hy};
        half8 k1 = {hz, (_Float16)0, (_Float16)0, (_Float16)0,
                    (_Float16)0, (_Float16)0, (_Float16)0, (_Float16)0};
        ((half8*)(ws + AKV_OFF))[idx * 2 + 0] = k0;
        ((half8*)(ws + AKV_OFF))[idx * 2 + 1] = k1;
    } else {
        int k = idx - NP * NM;
        float vx = cam[k * 3 + 0];
        float vy = cam[k * 3 + 1];
        float vz = cam[k * 3 + 2];
        ws[HB_OFF + k] = 0.5f * (vx * vx + vy * vy + vz * vz);
        _Float16 hx, lx, hy, ly, hz, lz;
        split16(vx, hx, lx);
        split16(vy, hy, ly);
        split16(vz, hz, lz);
        half8 k0 = {hx, hy, hz, hx, hy, hz, lx, ly};
        half8 k1 = {lz, (_Float16)0, (_Float16)0, (_Float16)0,
                    (_Float16)0, (_Float16)0, (_Float16)0, (_Float16)0};
        ((half8*)(ws + BKV_OFF))[k * 2 + 0] = k0;
        ((half8*)(ws + BKV_OFF))[k * 2 + 1] = k1;
    }

    if (idx < 64) {
        int p2 = idx >> 4;
        int r = (idx >> 2) & 3;
        int c = idx & 3;
        float T[12];
        make_transform(quat, tra, p2, T);
        float v;
        if (r == 3)
            v = (c == 3) ? 1.0f : 0.0f;
        else
            v = T[r * 4 + c];
        out[1 + idx] = v;
    } else if (idx == 64) {
        out[0] = 0.0f;
    }
}

// grid (32, 16, 4) x 256 threads (4 waves). Block tile: 256 m x 512 n.
// Wave w owns m-rows [mb+w*64, +64) = 4 i-tiles x all 32 j-tiles.
// NO GLOBAL ATOMICS (R11's 4.5x stall: cross-XCD atomicMin line ping-pong,
// WRITE 23.9 MB RMW amplification + vmcnt drain at block exit). Each block
// plain-stores its partial minima into a private slice: partA[by][p,m],
// partB[bx][p,n] -- unique writer per slot, coalesced, no init required.
// B-fragment prefetch depth 2 covers L2-hit latency (~200 cyc).
__global__ __launch_bounds__(256)
__attribute__((amdgpu_waves_per_eu(4, 8)))
void chamfer_mfma(const float* __restrict__ ws, float* __restrict__ part) {
    int tid = threadIdx.x;
    int lane = tid & 63;
    int w = tid >> 6;
    int quad = lane >> 4;
    int col = lane & 15;
    int p8 = blockIdx.z * 8192;
    int mb = blockIdx.x * 256;
    int nb = blockIdx.y * 512;
    const float INF = __uint_as_float(0x7f800000u);

    const half8* akv = (const half8*)(ws + AKV_OFF);
    const half8* bkv = (const half8*)(ws + BKV_OFF);
    const float* hap = ws + HA_OFF + p8;
    const float* hbp = ws + HB_OFF + p8;

    __shared__ float sMA[256];
    __shared__ float sMB[4 * 512];

    const half8 zf = {(_Float16)0, (_Float16)0, (_Float16)0, (_Float16)0,
                      (_Float16)0, (_Float16)0, (_Float16)0, (_Float16)0};

    int mw = mb + w * 64;
    half8 af[4];
    float4v haT[4];
    float4v minA[4];
#pragma unroll
    for (int i = 0; i < 4; ++i) {
        int m = mw + i * 16 + col;
        af[i] = (quad < 2) ? akv[(size_t)(p8 + m) * 2 + quad] : zf;
        haT[i] = *(const float4v*)(hap + mw + i * 16 + quad * 4);
        minA[i] = {INF, INF, INF, INF};
    }

    // Depth-2 register pipeline on the B fragment.
    int na = nb + col;
    int nbv = nb + 16 + col;
    half8 bf0 = (quad < 2) ? bkv[(size_t)(p8 + na) * 2 + quad] : zf;
    float hb0 = hbp[na];
    half8 bf1 = (quad < 2) ? bkv[(size_t)(p8 + nbv) * 2 + quad] : zf;
    float hb1 = hbp[nbv];

#pragma unroll 4
    for (int j = 0; j < 32; ++j) {
        int jn = (j + 2) & 31;  // tail iters harmlessly reload tiles 0,1
        int n = nb + jn * 16 + col;
        half8 bf2 = (quad < 2) ? bkv[(size_t)(p8 + n) * 2 + quad] : zf;
        float hb2 = hbp[n];

        float tb = INF;
#pragma unroll
        for (int i = 0; i < 4; ++i) {
            float4v c;
            c.x = haT[i].x + hb0;
            c.y = haT[i].y + hb0;
            c.z = haT[i].z + hb0;
            c.w = haT[i].w + hb0;
            c = __builtin_amdgcn_mfma_f32_16x16x32_f16(af[i], bf0, c, 0, 0, 0);
            minA[i].x = fminf(minA[i].x, c.x);
            minA[i].y = fminf(minA[i].y, c.y);
            minA[i].z = fminf(minA[i].z, c.z);
            minA[i].w = fminf(minA[i].w, c.w);
            tb = fminf(tb, fminf(fminf(c.x, c.y), fminf(c.z, c.w)));
        }
        // col-min for this j-tile: reduce across quads (rows), col fixed.
        tb = fminf(tb, __shfl_xor(tb, 16));
        tb = fminf(tb, __shfl_xor(tb, 32));
        if (lane < 16) sMB[w * 512 + j * 16 + col] = tb;

        bf0 = bf1; hb0 = hb1;
        bf1 = bf2; hb1 = hb2;
    }

    // minA: reduce across the 16 col-lanes of each quad; write per-wave rows.
#pragma unroll
    for (int i = 0; i < 4; ++i) {
        float v0 = minA[i].x, v1 = minA[i].y, v2 = minA[i].z, v3 = minA[i].w;
#pragma unroll
        for (int s = 1; s < 16; s <<= 1) {
            v0 = fminf(v0, __shfl_xor(v0, s));
            v1 = fminf(v1, __shfl_xor(v1, s));
            v2 = fminf(v2, __shfl_xor(v2, s));
            v3 = fminf(v3, __shfl_xor(v3, s));
        }
        if (col == 0) {
            float4v pack = {v0, v1, v2, v3};
            *(float4v*)&sMA[w * 64 + i * 16 + quad * 4] = pack;
        }
    }
    __syncthreads();

    // Private-slice partial stores (coalesced, no contention, no init).
    part[(size_t)(PARTA_OFF - PARTA_OFF) + (size_t)blockIdx.y * 32768 + p8 + mb + tid] = sMA[tid];
    float* partB = part + (PARTB_OFF - PARTA_OFF);
#pragma unroll
    for (int c = tid; c < 512; c += 256) {
        float v = fminf(fminf(sMB[c], sMB[512 + c]),
                        fminf(sMB[1024 + c], sMB[1536 + c]));
        partB[(size_t)blockIdx.x * 32768 + p8 + nb + c] = v;
    }
}

// 128 blocks x 256: merge partial slices, sqrt, weight, reduce.
__global__ __launch_bounds__(256) void finalize_kernel(
    const float* __restrict__ ws, const float* __restrict__ w,
    float* __restrict__ out) {
    const float* partA = ws + PARTA_OFF;
    const float* partB = ws + PARTB_OFF;
    int i = blockIdx.x * 256 + threadIdx.x;  // [0, 32768)
    int tid = threadIdx.x;
    const float INF = __uint_as_float(0x7f800000u);

    float va = INF;
#pragma unroll
    for (int s = 0; s < 16; ++s) va = fminf(va, partA[s * 32768 + i]);
    float vb = INF;
#pragma unroll
    for (int s = 0; s < 32; ++s) vb = fminf(vb, partB[s * 32768 + i]);

    float wp = w[(i >> 13) & 3];
    float acc = wp * (sqrtf(fmaxf(2.0f * va, 0.0f)) +
                      sqrtf(fmaxf(2.0f * vb, 0.0f)));

#pragma unroll
    for (int off = 32; off > 0; off >>= 1) acc += __shfl_down(acc, off, 64);

    __shared__ float wsum[4];
    if ((tid & 63) == 0) wsum[tid >> 6] = acc;
    __syncthreads();
    if (tid == 0) {
        float blocksum = (wsum[0] + wsum[1] + wsum[2] + wsum[3]) * (1.0f / 8192.0f);
        atomicAdd(out, blocksum);
    }
}

extern "C" void kernel_launch(void* const* d_in, const int* in_sizes, int n_in,
                              void* d_out, int out_size, void* d_ws, size_t ws_size,
                              hipStream_t stream) {
    const float* cam = (const float*)d_in[0];   // (P, N, 3)
    const float* cad = (const float*)d_in[1];   // (P, M, 3)
    const float* w = (const float*)d_in[2];     // (P,)
    const float* quat = (const float*)d_in[3];  // (P, 4)
    const float* tra = (const float*)d_in[4];   // (P, 3, 1)
    float* out = (float*)d_out;
    float* ws = (float*)d_ws;

    prep_kernel<<<256, 256, 0, stream>>>(cam, cad, quat, tra, ws, out);

    dim3 grid(NM / 256, NN / 512, NP);
    chamfer_mfma<<<grid, 256, 0, stream>>>(ws, ws + PARTA_OFF);

    finalize_kernel<<<128, 256, 0, stream>>>(ws, w, out);
}

// Round 13
// 104.811 us; speedup vs baseline: 1.4167x; 1.4167x over previous
//
#include <hip/hip_runtime.h>
#include <math.h>

#define NP 4
#define NN 8192
#define NM 8192

// ws layout (float units):
//   PKA: cad_t packed float4 (x,y,z,h) per point   at 0       (131072)
//   PKB: cam packed float4 per point               at 131072  (131072)
//   PRA: cad_t PAIRED: per pair {x0,x1,y0,y1},{z0,z1,h0,h1}  (131072)
//   PRB: cam PAIRED                                           (131072)
//   MINS: minA[32768] then minB[32768]                        (65536)
#define PKA_OFF 0
#define PKB_OFF 131072
#define PRA_OFF 262144
#define PRB_OFF 393216
#define MINS_OFF 524288
#define MINB_REL (NP * NM)
// total ws use: 589824 floats = 2.36 MB

#define TQ 8        // queries per thread
#define QT 2048     // queries per block (256 * TQ)
#define SPLITS 64   // target-dim splits -> grid (4,64,8) = 2048 blocks
#define SPAN 128    // targets per block (== NN/SPLITS)

typedef float float2v __attribute__((ext_vector_type(2)));
typedef float float4v __attribute__((ext_vector_type(4)));

__device__ inline float min3f(float a, float b, float c) {
    float d;
    asm("v_min3_f32 %0, %1, %2, %3" : "=v"(d) : "v"(a), "v"(b), "v"(c));
    return d;
}

// Packed fp32 FMA: d.lo = a.lo*b.lo+c.lo ; d.hi = a.hi*b.hi+c.hi (1 inst).
__device__ inline float2v pk_fma(float2v a, float2v b, float2v c) {
    float2v d;
    asm("v_pk_fma_f32 %0, %1, %2, %3" : "=v"(d) : "v"(a), "v"(b), "v"(c));
    return d;
}

__device__ inline void make_transform(const float* __restrict__ quat,
                                      const float* __restrict__ tra,
                                      int p, float T[12]) {
    float q0 = quat[p * 4 + 0], q1 = quat[p * 4 + 1];
    float q2 = quat[p * 4 + 2], q3 = quat[p * 4 + 3];
    float inv = 1.0f / sqrtf(q0 * q0 + q1 * q1 + q2 * q2 + q3 * q3);
    float a = q0 * inv, b = q1 * inv, c = q2 * inv, d = q3 * inv;
    T[0] = 1.0f - 2.0f * c * c - 2.0f * d * d;
    T[1] = 2.0f * b * c - 2.0f * a * d;
    T[2] = 2.0f * a * c + 2.0f * b * d;
    T[3] = tra[p * 3 + 0];
    T[4] = 2.0f * b * c + 2.0f * a * d;
    T[5] = 1.0f - 2.0f * b * b - 2.0f * d * d;
    T[6] = 2.0f * c * d - 2.0f * a * b;
    T[7] = tra[p * 3 + 1];
    T[8] = 2.0f * b * d - 2.0f * a * c;
    T[9] = 2.0f * a * b + 2.0f * c * d;
    T[10] = 1.0f - 2.0f * b * b - 2.0f * c * c;
    T[11] = tra[p * 3 + 2];
}

// 256 blocks x 256 threads over 65536 points: packed float4 (query use),
// PAIRED layout (target use), MINS init, transforms out, out[0]=0.
__global__ __launch_bounds__(256) void prep_kernel(
    const float* __restrict__ cam, const float* __restrict__ cad,
    const float* __restrict__ quat, const float* __restrict__ tra,
    float* __restrict__ ws, float* __restrict__ out) {
    int idx = blockIdx.x * 256 + threadIdx.x;  // [0, 65536)
    const float INF = __uint_as_float(0x7f800000u);

    float vx, vy, vz;
    int pkoff, proff, local;
    if (idx < NP * NM) {
        int p = idx >> 13;
        float T[12];
        make_transform(quat, tra, p, T);
        float x = cad[idx * 3 + 0];
        float y = cad[idx * 3 + 1];
        float z = cad[idx * 3 + 2];
        vx = fmaf(T[0], x, fmaf(T[1], y, fmaf(T[2], z, T[3])));
        vy = fmaf(T[4], x, fmaf(T[5], y, fmaf(T[6], z, T[7])));
        vz = fmaf(T[8], x, fmaf(T[9], y, fmaf(T[10], z, T[11])));
        pkoff = PKA_OFF;
        proff = PRA_OFF;
        local = idx;
    } else {
        int k = idx - NP * NM;
        vx = cam[k * 3 + 0];
        vy = cam[k * 3 + 1];
        vz = cam[k * 3 + 2];
        pkoff = PKB_OFF;
        proff = PRB_OFF;
        local = k;
    }
    float h = 0.5f * (vx * vx + vy * vy + vz * vz);
    ((float4*)(ws + pkoff))[local] = make_float4(vx, vy, vz, h);
    // paired layout: pair pp=local>>1, lane=local&1:
    //   quad 2pp   = {x0,x1,y0,y1}; quad 2pp+1 = {z0,z1,h0,h1}
    int lane = local & 1;
    size_t f = (size_t)proff + (size_t)(local & ~1) * 4;  // = (2pp)*4 floats
    ws[f + lane] = vx;
    ws[f + 2 + lane] = vy;
    ws[f + 4 + lane] = vz;
    ws[f + 6 + lane] = h;

    ws[MINS_OFF + idx] = INF;

    if (idx < 64) {
        int p2 = idx >> 4;
        int r = (idx >> 2) & 3;
        int c = idx & 3;
        float T[12];
        make_transform(quat, tra, p2, T);
        float v;
        if (r == 3)
            v = (c == 3) ? 1.0f : 0.0f;
        else
            v = T[r * 4 + c];
        out[1 + idx] = v;
    } else if (idx == 64) {
        out[0] = 0.0f;
    }
}

// grid (4, 64, 8) = 2048 blocks (R8 config). Targets staged to LDS in the
// PAIRED layout (broadcast reads, conflict-free, 1 ds_read_b128 per target
// -- unchanged LDS cost). v_pk_fma_f32 computes 2 targets per instruction:
// per 2 pairs = 3 pk_fma + 1 min3 = 2.0 VALU inst/pair vs R8's 3.5.
__global__ __launch_bounds__(256)
__attribute__((amdgpu_waves_per_eu(2, 4)))
void chamfer_kernel(const float* __restrict__ ws, float* __restrict__ mins) {
    int tid = threadIdx.x;
    int p = blockIdx.z >> 1;
    int role = blockIdx.z & 1;

    const float4* Q;
    const float4v* T;
    float* minarr;
    if (role == 0) {  // queries = cad_t, targets = cam -> minA
        Q = (const float4*)(ws + PKA_OFF) + p * NM;
        T = (const float4v*)(ws + PRB_OFF) + p * NN;  // 1 float4 per point
        minarr = mins + p * NM;
    } else {          // queries = cam, targets = cad_t -> minB
        Q = (const float4*)(ws + PKB_OFF) + p * NN;
        T = (const float4v*)(ws + PRA_OFF) + p * NM;
        minarr = mins + MINB_REL + p * NN;
    }

    __shared__ float4v sQd[SPAN];  // paired quads: [2pp]=XY, [2pp+1]=ZH

    const float INF = __uint_as_float(0x7f800000u);
    int q0 = blockIdx.x * QT + tid;
    float2v nqx[TQ], nqy[TQ], nqz[TQ];
    float qw[TQ], tmin[TQ];
#pragma unroll
    for (int k = 0; k < TQ; ++k) {
        float4 v = Q[q0 + k * 256];
        nqx[k] = (float2v){-v.x, -v.x};
        nqy[k] = (float2v){-v.y, -v.y};
        nqz[k] = (float2v){-v.z, -v.z};
        qw[k] = v.w;
        tmin[k] = INF;
    }

    int tbase = blockIdx.y * SPAN;  // float4-quad index == point index here
    if (tid < SPAN) sQd[tid] = T[tbase + tid];
    __syncthreads();

    float4v cXY = sQd[0], cZH = sQd[1];
#pragma unroll 2
    for (int pp = 0; pp < SPAN / 2; ++pp) {
        int pn = (pp + 1) & (SPAN / 2 - 1);  // last iter reloads pair 0
        float4v nXY = sQd[2 * pn];
        float4v nZH = sQd[2 * pn + 1];

        float2v X = __builtin_shufflevector(cXY, cXY, 0, 1);
        float2v Y = __builtin_shufflevector(cXY, cXY, 2, 3);
        float2v Z = __builtin_shufflevector(cZH, cZH, 0, 1);
        float2v H = __builtin_shufflevector(cZH, cZH, 2, 3);
#pragma unroll
        for (int k = 0; k < TQ; ++k) {
            float2v s = pk_fma(nqx[k], X, pk_fma(nqy[k], Y, pk_fma(nqz[k], Z, H)));
            tmin[k] = min3f(tmin[k], s.x, s.y);
        }
        cXY = nXY;
        cZH = nZH;
    }

#pragma unroll
    for (int k = 0; k < TQ; ++k) {
        float d2 = 2.0f * (qw[k] + tmin[k]);
        d2 = fmaxf(d2, 0.0f);
        atomicMin((unsigned int*)&minarr[q0 + k * 256], __float_as_uint(d2));
    }
}

__global__ __launch_bounds__(256) void finalize_kernel(
    const float* __restrict__ ws, const float* __restrict__ w,
    float* __restrict__ out) {
    // minA (NP*NM) then minB (NP*NN), contiguous 65536 floats at MINS_OFF.
    const float* vals = ws + MINS_OFF;
    int i = blockIdx.x * 256 + threadIdx.x;  // [0, 32768)
    int tid = threadIdx.x;

    float wl[4] = {w[0], w[1], w[2], w[3]};

    int i2 = i + 32768;
    float acc = wl[(i >> 13) & 3] * sqrtf(vals[i]) +
                wl[(i2 >> 13) & 3] * sqrtf(vals[i2]);

#pragma unroll
    for (int off = 32; off > 0; off >>= 1) acc += __shfl_down(acc, off, 64);

    __shared__ float wsum[4];
    if ((tid & 63) == 0) wsum[tid >> 6] = acc;
    __syncthreads();
    if (tid == 0) {
        float blocksum = (wsum[0] + wsum[1] + wsum[2] + wsum[3]) * (1.0f / 8192.0f);
        atomicAdd(out, blocksum);
    }
}

extern "C" void kernel_launch(void* const* d_in, const int* in_sizes, int n_in,
                              void* d_out, int out_size, void* d_ws, size_t ws_size,
                              hipStream_t stream) {
    const float* cam = (const float*)d_in[0];   // (P, N, 3)
    const float* cad = (const float*)d_in[1];   // (P, M, 3)
    const float* w = (const float*)d_in[2];     // (P,)
    const float* quat = (const float*)d_in[3];  // (P, 4)
    const float* tra = (const float*)d_in[4];   // (P, 3, 1)
    float* out = (float*)d_out;
    float* ws = (float*)d_ws;

    prep_kernel<<<256, 256, 0, stream>>>(cam, cad, quat, tra, ws, out);

    dim3 grid(NM / QT, SPLITS, 2 * NP);
    chamfer_kernel<<<grid, 256, 0, stream>>>(ws, ws + MINS_OFF);

    finalize_kernel<<<128, 256, 0, stream>>>(ws, w, out);
}